// Round 3
// baseline (91.989 us; speedup 1.0000x reference)
//
#include <hip/hip_runtime.h>

// Depth-4 path signature, B=128, L=128, C=12, fp32.
// Round 3: two-kernel structure.
//   prep_kernel: compute increments once -> d_ws in two layouts:
//     Draw[b][s][c]  (row-major, for uniform scalar loads in main loop)
//     DTg [b][c][s]  (transposed, staged to LDS for per-thread d_i/d_j/d_k)
//   sig_kernel: 256 blocks = (batch, i-half). Thread owns (i,j,k-pair),
//     accumulates two 12-element level-4 rows + s3 pair; s2,s1 redundant.
//     Block-uniform d[l] comes from SGPRs (s_load_dwordx16), NOT LDS
//     broadcasts -> LDS pipe demand drops ~5x. Transposed LDS table padded
//     to 33 float4/row -> residual conflicts <=2-way (free).
// No barriers in the 128-step main loop.

#define NC    12
#define NPTS  128
#define NSTEP 128            // 127 real increments + 1 zero pad (identity)
#define OUT_PER_B 22620      // 12 + 144 + 1728 + 20736
#define B1 384
#define B2 448               // 432 active = 6(i) * 12(j) * 6(k-pairs)
#define PADQ 33              // float4 row stride in LDS (528B -> banks shift 4/row)

__global__ __launch_bounds__(B1)
void prep_kernel(const float* __restrict__ path, float* __restrict__ Draw,
                 float* __restrict__ DTg) {
    const int b = blockIdx.x;
    const int t = threadIdx.x;        // < 384
    const int c  = t >> 5;            // 0..11
    const int sq = t & 31;            // 0..31
    const float* pb = path + (size_t)b * (NPTS * NC);
    float d[4];
    #pragma unroll
    for (int e = 0; e < 4; ++e) {
        int s = 4 * sq + e;
        d[e] = (s < NPTS - 1) ? (pb[(s + 1) * NC + c] - pb[s * NC + c]) : 0.f;
        Draw[(size_t)b * 1536 + s * NC + c] = d[e];
    }
    float4* dtg = (float4*)(DTg + (size_t)b * 1536 + c * NSTEP);
    dtg[sq] = make_float4(d[0], d[1], d[2], d[3]);
}

__global__ __launch_bounds__(B2)
void sig_kernel(const float* __restrict__ Draw, const float* __restrict__ DTg,
                float* __restrict__ out) {
    const int bid = blockIdx.x;
    const int b  = bid >> 1;
    const int ih = bid & 1;
    const int t  = threadIdx.x;

    __shared__ __align__(16) float4 DT4[NC * PADQ];   // 6336 B

    if (t < NC * 32) {
        int c = t >> 5, sq = t & 31;
        const float4* src = (const float4*)(DTg + (size_t)b * 1536 + c * NSTEP);
        DT4[c * PADQ + sq] = src[sq];
    }
    __syncthreads();

    // index map (duplicate work for pad threads; stores guarded later)
    const int ta  = (t < 432) ? t : (t - 432);
    const int il  = ta / 72;
    const int rem = ta - il * 72;
    const int j   = rem / 6;
    const int kh  = rem - j * 6;
    const int i   = ih * 6 + il;
    const int k0  = kh * 2;

    float acc0[12], acc1[12];
    #pragma unroll
    for (int l = 0; l < 12; ++l) { acc0[l] = 0.f; acc1[l] = 0.f; }
    float s3a = 0.f, s3b = 0.f, s2 = 0.f, s1 = 0.f;

    const float4* __restrict__ Dr = (const float4*)(Draw + (size_t)b * 1536);
    const float4* dti  = &DT4[i * PADQ];
    const float4* dtj  = &DT4[j * PADQ];
    const float4* dtka = &DT4[k0 * PADQ];
    const float4* dtkb = &DT4[(k0 + 1) * PADQ];

    for (int sq = 0; sq < NSTEP / 4; ++sq) {
        float4 di4  = dti[sq];
        float4 dj4  = dtj[sq];
        float4 dka4 = dtka[sq];
        float4 dkb4 = dtkb[sq];
        float4 w[12];                       // block-uniform -> SGPRs
        #pragma unroll
        for (int r = 0; r < 12; ++r) w[r] = Dr[sq * 12 + r];

        #pragma unroll
        for (int u = 0; u < 4; ++u) {
            const float di  = (&di4.x)[u];
            const float dj  = (&dj4.x)[u];
            const float dka = (&dka4.x)[u];
            const float dkb = (&dkb4.x)[u];

            // Horner-factored Chen step (identical arithmetic to round 2)
            float A4  = (s1 + 0.25f * di) * (1.f / 3.f);
            float B4  = (s2 + dj * A4) * 0.5f;
            float C3a = s3a + dka * B4;
            float C3b = s3b + dkb * B4;

            const float4 wa = w[3 * u + 0];
            const float4 wb = w[3 * u + 1];
            const float4 wc = w[3 * u + 2];
            acc0[0]  += C3a * wa.x;  acc0[1]  += C3a * wa.y;
            acc0[2]  += C3a * wa.z;  acc0[3]  += C3a * wa.w;
            acc0[4]  += C3a * wb.x;  acc0[5]  += C3a * wb.y;
            acc0[6]  += C3a * wb.z;  acc0[7]  += C3a * wb.w;
            acc0[8]  += C3a * wc.x;  acc0[9]  += C3a * wc.y;
            acc0[10] += C3a * wc.z;  acc0[11] += C3a * wc.w;
            acc1[0]  += C3b * wa.x;  acc1[1]  += C3b * wa.y;
            acc1[2]  += C3b * wa.z;  acc1[3]  += C3b * wa.w;
            acc1[4]  += C3b * wb.x;  acc1[5]  += C3b * wb.y;
            acc1[6]  += C3b * wb.z;  acc1[7]  += C3b * wb.w;
            acc1[8]  += C3b * wc.x;  acc1[9]  += C3b * wc.y;
            acc1[10] += C3b * wc.z;  acc1[11] += C3b * wc.w;

            float A3 = (s1 + di * (1.f / 3.f)) * 0.5f;
            float C2 = s2 + dj * A3;
            s3a += dka * C2;
            s3b += dkb * C2;
            s2  += dj * (s1 + 0.5f * di);
            s1  += di;
        }
    }

    if (t < 432) {
        float* ob = out + (size_t)b * OUT_PER_B;
        if (j == 0 && kh == 0) ob[i] = s1;                 // level 1
        if (kh == 0) ob[12 + i * 12 + j] = s2;             // level 2
        const int ijk = (i * 12 + j) * 12 + k0;
        ob[156 + ijk]     = s3a;                           // level 3
        ob[156 + ijk + 1] = s3b;
        float4* o4 = (float4*)(ob + 1884 + (size_t)ijk * 12);  // level 4, 96B
        o4[0] = make_float4(acc0[0], acc0[1], acc0[2],  acc0[3]);
        o4[1] = make_float4(acc0[4], acc0[5], acc0[6],  acc0[7]);
        o4[2] = make_float4(acc0[8], acc0[9], acc0[10], acc0[11]);
        o4[3] = make_float4(acc1[0], acc1[1], acc1[2],  acc1[3]);
        o4[4] = make_float4(acc1[4], acc1[5], acc1[6],  acc1[7]);
        o4[5] = make_float4(acc1[8], acc1[9], acc1[10], acc1[11]);
    }
}

extern "C" void kernel_launch(void* const* d_in, const int* in_sizes, int n_in,
                              void* d_out, int out_size, void* d_ws, size_t ws_size,
                              hipStream_t stream) {
    const float* path = (const float*)d_in[0];
    float* out = (float*)d_out;
    const int nbatch = in_sizes[0] / (NPTS * NC);   // = 128

    float* Draw = (float*)d_ws;                      // 128*1536 floats
    float* DTg  = Draw + (size_t)nbatch * 1536;      // 128*1536 floats

    prep_kernel<<<nbatch, B1, 0, stream>>>(path, Draw, DTg);
    sig_kernel<<<nbatch * 2, B2, 0, stream>>>(Draw, DTg, out);
}

// Round 5
// 78.747 us; speedup vs baseline: 1.1682x; 1.1682x over previous
//
#include <hip/hip_runtime.h>

// Depth-4 path signature, B=128, L=128, C=12, fp32.
// Round 5: R4 retry with the asm constraint bug fixed — the s_load address
// is explicitly uniformized via __builtin_amdgcn_readfirstlane so the "s"
// operand is genuinely in an SGPR pair. Block-uniform increment rows load
// with s_load_dwordx16 into SGPRs (scalar K$), so level-4 FMAs are
// v_fmac_f32 vacc, s_w, vC3 — zero LDS/VMEM pipe cost for the broadcast data.
//   prep_kernel: increments -> d_ws (row-major Draw + transposed DTg).
//   sig_kernel: 256 blocks = (batch, i-half); thread owns (i,j,k-pair),
//     24 level-4 acc FMAs/step; transposed LDS table padded (<=2-way, free).
// No barriers in the 128-step main loop.

#define NC    12
#define NPTS  128
#define NSTEP 128            // 127 real increments + 1 zero pad (identity)
#define OUT_PER_B 22620      // 12 + 144 + 1728 + 20736
#define B1 384
#define B2 448               // 432 active = 6(i) * 12(j) * 6(k-pairs)
#define PADQ 33              // float4 row stride in LDS

typedef float vf16 __attribute__((ext_vector_type(16)));

// constant-foldable element access into the 3 SGPR vectors (e in [0,48))
#define WGET(e) ((e) < 16 ? w0[(e) & 15] : ((e) < 32 ? w1[(e) & 15] : w2[(e) & 15]))

__global__ __launch_bounds__(B1)
void prep_kernel(const float* __restrict__ path, float* __restrict__ Draw,
                 float* __restrict__ DTg) {
    const int b = blockIdx.x;
    const int t = threadIdx.x;        // < 384
    const int c  = t >> 5;            // 0..11
    const int sq = t & 31;            // 0..31
    const float* pb = path + (size_t)b * (NPTS * NC);
    float d[4];
    #pragma unroll
    for (int e = 0; e < 4; ++e) {
        int s = 4 * sq + e;
        d[e] = (s < NPTS - 1) ? (pb[(s + 1) * NC + c] - pb[s * NC + c]) : 0.f;
        Draw[(size_t)b * 1536 + s * NC + c] = d[e];
    }
    float4* dtg = (float4*)(DTg + (size_t)b * 1536 + c * NSTEP);
    dtg[sq] = make_float4(d[0], d[1], d[2], d[3]);
}

__global__ __launch_bounds__(B2)
void sig_kernel(const float* __restrict__ Draw, const float* __restrict__ DTg,
                float* __restrict__ out) {
    const int bid = blockIdx.x;
    const int b  = bid >> 1;
    const int ih = bid & 1;
    const int t  = threadIdx.x;

    __shared__ __align__(16) float4 DT4[NC * PADQ];   // 6336 B

    if (t < NC * 32) {
        int c = t >> 5, sq = t & 31;
        const float4* src = (const float4*)(DTg + (size_t)b * 1536 + c * NSTEP);
        DT4[c * PADQ + sq] = src[sq];
    }
    __syncthreads();

    // index map (pad threads duplicate work; stores guarded later)
    const int ta  = (t < 432) ? t : (t - 432);
    const int il  = ta / 72;
    const int rem = ta - il * 72;
    const int j   = rem / 6;
    const int kh  = rem - j * 6;
    const int i   = ih * 6 + il;
    const int k0  = kh * 2;

    float acc0[12], acc1[12];
    #pragma unroll
    for (int l = 0; l < 12; ++l) { acc0[l] = 0.f; acc1[l] = 0.f; }
    float s3a = 0.f, s3b = 0.f, s2 = 0.f, s1 = 0.f;

    // Uniformize the block's increment-table base address ONCE into an
    // SGPR pair; per-iteration offsets are immediates in the s_load.
    unsigned long long base_u;
    {
        unsigned long long a = (unsigned long long)(Draw + (size_t)b * 1536);
        unsigned int lo = __builtin_amdgcn_readfirstlane((unsigned int)a);
        unsigned int hi = __builtin_amdgcn_readfirstlane((unsigned int)(a >> 32));
        base_u = ((unsigned long long)hi << 32) | lo;
    }

    const float4* dti  = &DT4[i * PADQ];
    const float4* dtj  = &DT4[j * PADQ];
    const float4* dtka = &DT4[k0 * PADQ];
    const float4* dtkb = &DT4[(k0 + 1) * PADQ];

    for (int sq = 0; sq < NSTEP / 4; ++sq) {
        // block-uniform 48 increments for these 4 steps -> SGPRs via s_load.
        vf16 w0, w1, w2;
        {
            const float* wp = (const float*)(base_u + (unsigned long long)(sq * 192));
            asm volatile(
                "s_load_dwordx16 %0, %3, 0x0\n\t"
                "s_load_dwordx16 %1, %3, 0x40\n\t"
                "s_load_dwordx16 %2, %3, 0x80\n\t"
                "s_waitcnt lgkmcnt(0)"
                : "=&s"(w0), "=&s"(w1), "=&s"(w2)
                : "s"(wp));
        }

        // per-thread transposed reads (LDS, <=2-way conflict = free)
        float4 di4  = dti[sq];
        float4 dj4  = dtj[sq];
        float4 dka4 = dtka[sq];
        float4 dkb4 = dtkb[sq];

        #pragma unroll
        for (int u = 0; u < 4; ++u) {
            const float di  = (&di4.x)[u];
            const float dj  = (&dj4.x)[u];
            const float dka = (&dka4.x)[u];
            const float dkb = (&dkb4.x)[u];

            // Horner-factored Chen step (identical arithmetic to R2/R3)
            float A4  = (s1 + 0.25f * di) * (1.f / 3.f);
            float B4  = (s2 + dj * A4) * 0.5f;
            float C3a = s3a + dka * B4;
            float C3b = s3b + dkb * B4;

            #pragma unroll
            for (int l = 0; l < 12; ++l) {
                const float wl = WGET(12 * u + l);   // SGPR operand
                acc0[l] += C3a * wl;
                acc1[l] += C3b * wl;
            }

            float A3 = (s1 + di * (1.f / 3.f)) * 0.5f;
            float C2 = s2 + dj * A3;
            s3a += dka * C2;
            s3b += dkb * C2;
            s2  += dj * (s1 + 0.5f * di);
            s1  += di;
        }
    }

    if (t < 432) {
        float* ob = out + (size_t)b * OUT_PER_B;
        if (j == 0 && kh == 0) ob[i] = s1;                 // level 1
        if (kh == 0) ob[12 + i * 12 + j] = s2;             // level 2
        const int ijk = (i * 12 + j) * 12 + k0;
        ob[156 + ijk]     = s3a;                           // level 3
        ob[156 + ijk + 1] = s3b;
        float4* o4 = (float4*)(ob + 1884 + (size_t)ijk * 12);  // level 4, 96B
        o4[0] = make_float4(acc0[0], acc0[1], acc0[2],  acc0[3]);
        o4[1] = make_float4(acc0[4], acc0[5], acc0[6],  acc0[7]);
        o4[2] = make_float4(acc0[8], acc0[9], acc0[10], acc0[11]);
        o4[3] = make_float4(acc1[0], acc1[1], acc1[2],  acc1[3]);
        o4[4] = make_float4(acc1[4], acc1[5], acc1[6],  acc1[7]);
        o4[5] = make_float4(acc1[8], acc1[9], acc1[10], acc1[11]);
    }
}

extern "C" void kernel_launch(void* const* d_in, const int* in_sizes, int n_in,
                              void* d_out, int out_size, void* d_ws, size_t ws_size,
                              hipStream_t stream) {
    const float* path = (const float*)d_in[0];
    float* out = (float*)d_out;
    const int nbatch = in_sizes[0] / (NPTS * NC);   // = 128

    float* Draw = (float*)d_ws;                      // 128*1536 floats
    float* DTg  = Draw + (size_t)nbatch * 1536;      // 128*1536 floats

    prep_kernel<<<nbatch, B1, 0, stream>>>(path, Draw, DTg);
    sig_kernel<<<nbatch * 2, B2, 0, stream>>>(Draw, DTg, out);
}